// Round 11
// baseline (1004.526 us; speedup 1.0000x reference)
//
#include <hip/hip_runtime.h>

// SKA3D: x [B=2, C=64, D=64, H=64, W=64] fp32; w [B=2, G=8, 27, D, H, W] fp32
// out[b,c,d,h,w] = sum_k x[b,c,(d+di)%64,(h+hi)%64,(w+wi)%64] * w[b,c/8,k,d,h,w]
//
// R11 = R9's proven skeleton with the sliding axis swapped d->h for DRAM row
// locality of the dominant w stream: iterating h, each (tap,d) w-stream
// advances 256 B/iter (sequential) instead of 16 KB/iter (row-thrash).
//  - lane = 16 w-strips x 4 d-offsets; block = (b,g, d-tile of 4, h-chunk 16)
//  - 4-slot h-ring in LDS: [slot][c][dr][w] = 4x8x6x64 = 48 KB (dr = d-1..d+4)
//  - DPP W-halos (row_ror within 16-lane strips), b128-only LDS reads
//  - wk[27] single-buffered, loaded MONOLITHICALLY at loop end (R6/R7/R10
//    lesson: chunked mid-compute reload makes the scheduler hoist loads above
//    the consuming phase -> double live range -> spill-everything, 5x slower)
//  - amdgpu_waves_per_eu(2,3), 3 blocks/CU; raw s_barrier + counted vmcnt
//
// Per-wave per-iter VMEM order: stage(3), wk(27), stores(2).
// [A] vmcnt(29) drains my stage(h+1) (newer: 27 wk + 2 stores = 29).
// [B] s_barrier -> slot h+1 globally ready AND nobody still reads slot (h+2)&3.

#define ND 64
#define NH 64
#define NW 64
#define HW 4096
#define DHW 262144

typedef const __attribute__((address_space(1))) unsigned int* gp_as1;
typedef __attribute__((address_space(3))) unsigned int* lp_as3;
typedef float f32x4 __attribute__((ext_vector_type(4)));

__device__ __forceinline__ float dpp_prev(float v) {   // lane j <- lane (j-1)&15
    int i = __builtin_bit_cast(int, v);
    i = __builtin_amdgcn_update_dpp(i, i, 0x121, 0xF, 0xF, true);  // row_ror:1
    return __builtin_bit_cast(float, i);
}
__device__ __forceinline__ float dpp_next(float v) {   // lane j <- lane (j+1)&15
    int i = __builtin_bit_cast(int, v);
    i = __builtin_amdgcn_update_dpp(i, i, 0x12F, 0xF, 0xF, true);  // row_ror:15
    return __builtin_bit_cast(float, i);
}

__global__ __launch_bounds__(256)
__attribute__((amdgpu_waves_per_eu(2, 3)))
void ska3d_kernel(const float* __restrict__ x,
                  const float* __restrict__ w,
                  float* __restrict__ out) {
    __shared__ float lds[4][8][6][NW];     // [slot][c][dr][w] 48 KB

    const int tid  = threadIdx.x;          // 0..255
    const int lane = tid & 63;
    const int wv   = tid >> 6;             // wave id 0..3
    const int w0   = (lane & 15) * 4;      // w strip start
    const int dl   = lane >> 4;            // d offset within tile, 0..3
    const int c0   = wv * 2;               // this wave's channels

    const int bid = blockIdx.x;
    const int hc  = bid & 3;               // h-chunk (16 h each)
    const int dt  = (bid >> 2) & 15;       // d-tile (4 d each)
    const int g   = (bid >> 6) & 7;
    const int b   = bid >> 9;

    const int h0 = hc * 16;
    const int d0 = dt * 4;
    const int d  = d0 + dl;                // this lane's output d

    const float* xb = x + (size_t)(b * 64 + g * 8) * DHW;
    const float* wb = w + (size_t)(b * 8 + g) * 27 * DHW + d * HW + w0;
    float* ob = out + (size_t)(b * 64 + g * 8 + c0) * DHW + d * HW + w0;

    // stage h-plane p (slot = p&3, global hh = p&63): x[c][d0-1+dr][hh][*]
    // 8c x 6dr x 16 units(16B) = 768 units, 256 threads -> 3 ops/thread.
    // LDS dest is linear in fid (lane-consecutive) as global_load_lds needs.
#define STAGE(p) do {                                                          \
        const int slot_ = (p) & 3;                                             \
        const int hh_   = (p) & 63;                                            \
        _Pragma("unroll")                                                      \
        for (int i_ = 0; i_ < 3; ++i_) {                                       \
            const int fid = i_ * 256 + tid;    /* 0..767 */                    \
            const int c_  = fid / 96;                                          \
            const int rm_ = fid - c_ * 96;                                     \
            const int dr_ = rm_ >> 4;          /* 0..5 */                      \
            const int ws_ = rm_ & 15;          /* 0..15 */                     \
            const int dd_ = (d0 - 1 + dr_) & 63;                               \
            const float* gsrc = xb + (size_t)c_ * DHW + dd_ * HW + hh_ * NW + ws_ * 4; \
            __builtin_amdgcn_global_load_lds((gp_as1)gsrc,                     \
                (lp_as3)&lds[slot_][c_][dr_][ws_ * 4], 16, 0, 0);              \
        }                                                                      \
    } while (0)

    // all 27 taps for h-row hp (0..63, no wrap needed inside a chunk)
#define LOADW(hp) do {                                                         \
        const float* wp_ = wb + (size_t)(hp) * NW;                             \
        _Pragma("unroll")                                                      \
        for (int k_ = 0; k_ < 27; ++k_)                                        \
            wk[k_] = *(const float4*)(wp_ + (size_t)k_ * DHW);                 \
    } while (0)

    float4 wk[27];

    // prologue: h-planes h0-1, h0, h0+1 staged; wk(h0) loaded; full drain
    STAGE(h0 - 1);
    STAGE(h0);
    STAGE(h0 + 1);
    LOADW(h0);
    asm volatile("s_waitcnt vmcnt(0)" ::: "memory");

#pragma unroll 1
    for (int i = 0; i < 16; ++i) {
        const int h = h0 + i;

        // [A] drain my stage(h+1); newer ops = 27 wk + 2 stores = 29
        asm volatile("s_waitcnt vmcnt(29)" ::: "memory");
        // [B] all waves' stage(h+1) done; all waves done reading slot (h+2)&3
        asm volatile("s_barrier" ::: "memory");

        // [C] prefetch h-plane h+2 into slot (h+2)&3 (disjoint from h-1,h,h+1)
        if (i < 15) STAGE(h + 2);

        // [D] compute row h: phases over hi (ring slots), di within phase
        float acc[2][4];
#pragma unroll
        for (int cc = 0; cc < 2; ++cc)
            acc[cc][0] = acc[cc][1] = acc[cc][2] = acc[cc][3] = 0.f;

#pragma unroll
        for (int hi = -1; hi <= 1; ++hi) {
            const int slot = (h + hi) & 3;
#pragma unroll
            for (int di = -1; di <= 1; ++di) {
                const int dr = dl + di + 1;            // 0..5
                const int kb = (di + 1) * 9 + (hi + 1) * 3;
#pragma unroll
                for (int cc = 0; cc < 2; ++cc) {
                    const float* row = &lds[slot][c0 + cc][dr][0];
                    const float4 xv = *(const float4*)(row + w0);
                    const float  xm = dpp_prev(xv.w);   // x[w0-1] circular
                    const float  xp = dpp_next(xv.x);   // x[w0+4] circular
                    const float4 wa = wk[kb], wm = wk[kb + 1], wc = wk[kb + 2];
                    acc[cc][0] += wa.x * xm;    acc[cc][1] += wa.y * xv.x;
                    acc[cc][2] += wa.z * xv.y;  acc[cc][3] += wa.w * xv.z;
                    acc[cc][0] += wm.x * xv.x;  acc[cc][1] += wm.y * xv.y;
                    acc[cc][2] += wm.z * xv.z;  acc[cc][3] += wm.w * xv.w;
                    acc[cc][0] += wc.x * xv.y;  acc[cc][1] += wc.y * xv.z;
                    acc[cc][2] += wc.z * xv.w;  acc[cc][3] += wc.w * xp;
                }
            }
        }

        // [E] wk(h+1) for next iter (monolithic; before stores for extra lead)
        if (i < 15) LOADW(h + 1);

        // [F] nontemporal stores (out is never re-read)
#pragma unroll
        for (int cc = 0; cc < 2; ++cc) {
            f32x4 v;
            v.x = acc[cc][0]; v.y = acc[cc][1]; v.z = acc[cc][2]; v.w = acc[cc][3];
            __builtin_nontemporal_store(v,
                (f32x4*)(ob + (size_t)cc * DHW + (size_t)h * NW));
        }
    }
}

extern "C" void kernel_launch(void* const* d_in, const int* in_sizes, int n_in,
                              void* d_out, int out_size, void* d_ws, size_t ws_size,
                              hipStream_t stream) {
    const float* x = (const float*)d_in[0];
    const float* w = (const float*)d_in[1];
    float* out = (float*)d_out;
    // grid: b(2) x g(8) x d-tiles(16) x h-chunks(4) = 1024 blocks of 256
    dim3 grid(1024);
    dim3 block(256);
    hipLaunchKernelGGL(ska3d_kernel, grid, block, 0, stream, x, w, out);
}

// Round 12
// 171.461 us; speedup vs baseline: 5.8586x; 5.8586x over previous
//
#include <hip/hip_runtime.h>

// SKA3D: x [B=2, C=64, D=64, H=64, W=64] fp32; w [B=2, G=8, 27, D, H, W] fp32
// out[b,c,d,h,w] = sum_k x[b,c,(d+di)%64,(h+hi)%64,(w+wi)%64] * w[b,c/8,k,d,h,w]
//
// R12 = R11 (h-sliding ring: w stream advances 256 B/iter -> sequential DRAM
// runs for the dominant 432 MB w stream) with the R11 spill mechanism removed:
//  - stores issued BEFORE LOADW (exact R9 ordering; R11 had LOADW first and
//    the scheduler hoisted the 27-load batch into compute -> old+new wk both
//    live -> spill-everything, 6x slowdown. R6/R7/R10 same disease.)
//  - sched_barrier(0) immediately before LOADW: compile-time fence, the
//    hoist becomes impossible rather than merely unattractive.
//  - lane = 16 w-strips x 4 d-offsets; block = (b, g, d-tile of 4, h-chunk 16)
//  - 4-slot h-ring in LDS: [slot][c][dr][w] = 4x8x6x64 = 48 KB (dr = d-1..d+4)
//  - DPP W-halos, b128-only LDS reads; wk[27] single-buffered, monolithic
//  - raw s_barrier + counted vmcnt; nontemporal stores; waves_per_eu(2,3)
//
// Per-wave per-iter VMEM order: stage(3), stores(2), wk(27).
// [A] vmcnt(29) drains my stage(h+1) (newer: 2 stores + 27 wk = 29).
// [B] s_barrier -> slot h+1 globally ready AND nobody still reads slot (h+2)&3.

#define ND 64
#define NH 64
#define NW 64
#define HW 4096
#define DHW 262144

typedef const __attribute__((address_space(1))) unsigned int* gp_as1;
typedef __attribute__((address_space(3))) unsigned int* lp_as3;
typedef float f32x4 __attribute__((ext_vector_type(4)));

__device__ __forceinline__ float dpp_prev(float v) {   // lane j <- lane (j-1)&15
    int i = __builtin_bit_cast(int, v);
    i = __builtin_amdgcn_update_dpp(i, i, 0x121, 0xF, 0xF, true);  // row_ror:1
    return __builtin_bit_cast(float, i);
}
__device__ __forceinline__ float dpp_next(float v) {   // lane j <- lane (j+1)&15
    int i = __builtin_bit_cast(int, v);
    i = __builtin_amdgcn_update_dpp(i, i, 0x12F, 0xF, 0xF, true);  // row_ror:15
    return __builtin_bit_cast(float, i);
}

__global__ __launch_bounds__(256)
__attribute__((amdgpu_waves_per_eu(2, 3)))
void ska3d_kernel(const float* __restrict__ x,
                  const float* __restrict__ w,
                  float* __restrict__ out) {
    __shared__ float lds[4][8][6][NW];     // [slot][c][dr][w] 48 KB

    const int tid  = threadIdx.x;          // 0..255
    const int lane = tid & 63;
    const int wv   = tid >> 6;             // wave id 0..3
    const int w0   = (lane & 15) * 4;      // w strip start
    const int dl   = lane >> 4;            // d offset within tile, 0..3
    const int c0   = wv * 2;               // this wave's channels

    const int bid = blockIdx.x;
    const int hc  = bid & 3;               // h-chunk (16 h each)
    const int dt  = (bid >> 2) & 15;       // d-tile (4 d each)
    const int g   = (bid >> 6) & 7;
    const int b   = bid >> 9;

    const int h0 = hc * 16;
    const int d0 = dt * 4;
    const int d  = d0 + dl;                // this lane's output d

    const float* xb = x + (size_t)(b * 64 + g * 8) * DHW;
    const float* wb = w + (size_t)(b * 8 + g) * 27 * DHW + d * HW + w0;
    float* ob = out + (size_t)(b * 64 + g * 8 + c0) * DHW + d * HW + w0;

    // stage h-plane p (slot = p&3, global hh = p&63): x[c][d0-1+dr][hh][*]
    // 8c x 6dr x 16 units(16B) = 768 units, 256 threads -> 3 ops/thread.
#define STAGE(p) do {                                                          \
        const int slot_ = (p) & 3;                                             \
        const int hh_   = (p) & 63;                                            \
        _Pragma("unroll")                                                      \
        for (int i_ = 0; i_ < 3; ++i_) {                                       \
            const int fid = i_ * 256 + tid;    /* 0..767 */                    \
            const int c_  = fid / 96;                                          \
            const int rm_ = fid - c_ * 96;                                     \
            const int dr_ = rm_ >> 4;          /* 0..5 */                      \
            const int ws_ = rm_ & 15;          /* 0..15 */                     \
            const int dd_ = (d0 - 1 + dr_) & 63;                               \
            const float* gsrc = xb + (size_t)c_ * DHW + dd_ * HW + hh_ * NW + ws_ * 4; \
            __builtin_amdgcn_global_load_lds((gp_as1)gsrc,                     \
                (lp_as3)&lds[slot_][c_][dr_][ws_ * 4], 16, 0, 0);              \
        }                                                                      \
    } while (0)

    // all 27 taps for h-row hp (0..63, no wrap needed inside a chunk)
#define LOADW(hp) do {                                                         \
        const float* wp_ = wb + (size_t)(hp) * NW;                             \
        _Pragma("unroll")                                                      \
        for (int k_ = 0; k_ < 27; ++k_)                                        \
            wk[k_] = *(const float4*)(wp_ + (size_t)k_ * DHW);                 \
    } while (0)

    float4 wk[27];

    // prologue: h-planes h0-1, h0, h0+1 staged; wk(h0) loaded; full drain
    STAGE(h0 - 1);
    STAGE(h0);
    STAGE(h0 + 1);
    LOADW(h0);
    asm volatile("s_waitcnt vmcnt(0)" ::: "memory");

#pragma unroll 1
    for (int i = 0; i < 16; ++i) {
        const int h = h0 + i;

        // [A] drain my stage(h+1); newer ops = 2 stores + 27 wk = 29
        asm volatile("s_waitcnt vmcnt(29)" ::: "memory");
        // [B] all waves' stage(h+1) done; all waves done reading slot (h+2)&3
        asm volatile("s_barrier" ::: "memory");

        // [C] prefetch h-plane h+2 into slot (h+2)&3 (disjoint from h-1,h,h+1)
        if (i < 15) STAGE(h + 2);

        // [D] compute row h: phases over hi (ring slots), di within phase
        float acc[2][4];
#pragma unroll
        for (int cc = 0; cc < 2; ++cc)
            acc[cc][0] = acc[cc][1] = acc[cc][2] = acc[cc][3] = 0.f;

#pragma unroll
        for (int hi = -1; hi <= 1; ++hi) {
            const int slot = (h + hi) & 3;
#pragma unroll
            for (int di = -1; di <= 1; ++di) {
                const int dr = dl + di + 1;            // 0..5
                const int kb = (di + 1) * 9 + (hi + 1) * 3;
#pragma unroll
                for (int cc = 0; cc < 2; ++cc) {
                    const float* row = &lds[slot][c0 + cc][dr][0];
                    const float4 xv = *(const float4*)(row + w0);
                    const float  xm = dpp_prev(xv.w);   // x[w0-1] circular
                    const float  xp = dpp_next(xv.x);   // x[w0+4] circular
                    const float4 wa = wk[kb], wm = wk[kb + 1], wc = wk[kb + 2];
                    acc[cc][0] += wa.x * xm;    acc[cc][1] += wa.y * xv.x;
                    acc[cc][2] += wa.z * xv.y;  acc[cc][3] += wa.w * xv.z;
                    acc[cc][0] += wm.x * xv.x;  acc[cc][1] += wm.y * xv.y;
                    acc[cc][2] += wm.z * xv.z;  acc[cc][3] += wm.w * xv.w;
                    acc[cc][0] += wc.x * xv.y;  acc[cc][1] += wc.y * xv.z;
                    acc[cc][2] += wc.z * xv.w;  acc[cc][3] += wc.w * xp;
                }
            }
        }

        // [E] nontemporal stores FIRST (R9 ordering — the no-spill shape)
#pragma unroll
        for (int cc = 0; cc < 2; ++cc) {
            f32x4 v;
            v.x = acc[cc][0]; v.y = acc[cc][1]; v.z = acc[cc][2]; v.w = acc[cc][3];
            __builtin_nontemporal_store(v,
                (f32x4*)(ob + (size_t)cc * DHW + (size_t)h * NW));
        }

        // [F] wk(h+1) last; fence forbids hoisting these loads into compute
        //     (the hoist doubles wk's live range -> spill: R6/R7/R10/R11)
        __builtin_amdgcn_sched_barrier(0);
        if (i < 15) LOADW(h + 1);
    }
}

extern "C" void kernel_launch(void* const* d_in, const int* in_sizes, int n_in,
                              void* d_out, int out_size, void* d_ws, size_t ws_size,
                              hipStream_t stream) {
    const float* x = (const float*)d_in[0];
    const float* w = (const float*)d_in[1];
    float* out = (float*)d_out;
    // grid: b(2) x g(8) x d-tiles(16) x h-chunks(4) = 1024 blocks of 256
    dim3 grid(1024);
    dim3 block(256);
    hipLaunchKernelGGL(ska3d_kernel, grid, block, 0, stream, x, w, out);
}

// Round 13
// 158.061 us; speedup vs baseline: 6.3553x; 1.0848x over previous
//
#include <hip/hip_runtime.h>

// SKA3D: x [B=2, C=64, D=64, H=64, W=64] fp32; w [B=2, G=8, 27, D, H, W] fp32
// out[b,c,d,h,w] = sum_k x[b,c,(d+di)%64,(h+hi)%64,(w+wi)%64] * w[b,c/8,k,d,h,w]
//
// R13 = R9 (champion, 156.3 us) with d-chunk 8 -> 16:
//  - prologue (3-plane stage + vmcnt(0) drain + first wk) amortized over 16
//    iters instead of 8 (~11% -> ~5% of block runtime)
//  - d-halo staging overhead 10/8 -> 18/16 planes: x traffic 240 -> 216 MB
//  - inner loop / registers / LDS / vmcnt accounting BIT-IDENTICAL to R9
// R9 skeleton: 4-wave block, 2 ch/wave, 4-slot d-ring 48 KB, DPP W-halos,
// b128-only LDS reads, wk[27] single-buffered loaded monolithically at loop
// end (R6/R7/R10/R11 lesson: any other wk shape spills), raw s_barrier +
// counted vmcnt, nontemporal stores, waves_per_eu(2,3) -> 3 blocks/CU.
// sched_barrier(0) before LOADW (R12-proven harmless insurance vs hoist).
//
// Per-wave per-iter VMEM order: stage(3), stores(2), wk(27).
// [A] vmcnt(29) drains my stage(d+1) (newer: 2 stores + 27 wk = 29).
// [B] s_barrier -> slot d+1 globally ready AND nobody still reads slot (d+2)&3.

#define ND 64
#define NH 64
#define NW 64
#define HW 4096
#define DHW 262144

typedef const __attribute__((address_space(1))) unsigned int* gp_as1;
typedef __attribute__((address_space(3))) unsigned int* lp_as3;
typedef float f32x4 __attribute__((ext_vector_type(4)));

__device__ __forceinline__ float dpp_prev(float v) {   // lane j <- lane (j-1)&15
    int i = __builtin_bit_cast(int, v);
    i = __builtin_amdgcn_update_dpp(i, i, 0x121, 0xF, 0xF, true);  // row_ror:1
    return __builtin_bit_cast(float, i);
}
__device__ __forceinline__ float dpp_next(float v) {   // lane j <- lane (j+1)&15
    int i = __builtin_bit_cast(int, v);
    i = __builtin_amdgcn_update_dpp(i, i, 0x12F, 0xF, 0xF, true);  // row_ror:15
    return __builtin_bit_cast(float, i);
}

__global__ __launch_bounds__(256)
__attribute__((amdgpu_waves_per_eu(2, 3)))
void ska3d_kernel(const float* __restrict__ x,
                  const float* __restrict__ w,
                  float* __restrict__ out) {
    __shared__ float lds[4][8][6][NW];     // [slot][c][r][w] 48 KB

    const int tid  = threadIdx.x;          // 0..255
    const int lane = tid & 63;
    const int wv   = tid >> 6;             // wave id 0..3
    const int w0   = (lane & 15) * 4;      // w strip start
    const int hl   = lane >> 4;            // 0..3
    const int c0   = wv * 2;               // this wave's channels

    const int bid = blockIdx.x;
    const int dc  = bid & 3;               // d-chunk (16 planes)
    const int ht  = (bid >> 2) & 15;       // h-tile (4 rows)
    const int g   = (bid >> 6) & 7;
    const int b   = bid >> 9;

    const int d0 = dc * 16;
    const int h0 = ht * 4;
    const int h  = h0 + hl;

    const float* xb = x + (size_t)(b * 64 + g * 8) * DHW;
    const float* wb = w + (size_t)(b * 8 + g) * 27 * DHW + h * NW + w0;
    float* ob = out + (size_t)(b * 64 + g * 8 + c0) * DHW + h * NW + w0;

    // stage plane p: 768 16B-units, 256 threads -> 3 ops/thread
#define STAGE(p) do {                                                          \
        const int slot_ = (p) & 3;                                             \
        const int dd_   = (p) & 63;                                            \
        _Pragma("unroll")                                                      \
        for (int i_ = 0; i_ < 3; ++i_) {                                       \
            const int fid = i_ * 256 + tid;    /* 0..767 */                    \
            const int c_  = fid / 96;                                          \
            const int rm_ = fid - c_ * 96;                                     \
            const int r_  = rm_ >> 4;          /* 0..5 */                      \
            const int ws_ = rm_ & 15;          /* 0..15 */                     \
            const int hh_ = (h0 - 1 + r_) & 63;                                \
            const float* gsrc = xb + (size_t)c_ * DHW + dd_ * HW + hh_ * NW + ws_ * 4; \
            __builtin_amdgcn_global_load_lds((gp_as1)gsrc,                     \
                (lp_as3)&lds[slot_][c_][r_][ws_ * 4], 16, 0, 0);               \
        }                                                                      \
    } while (0)

#define LOADW(dp) do {                                                         \
        const float* wp_ = wb + (size_t)(dp) * HW;                             \
        _Pragma("unroll")                                                      \
        for (int k_ = 0; k_ < 27; ++k_)                                        \
            wk[k_] = *(const float4*)(wp_ + (size_t)k_ * DHW);                 \
    } while (0)

    float4 wk[27];

    // prologue: planes d0-1, d0, d0+1 staged; wk(d0) loaded; full drain
    STAGE(d0 - 1);
    STAGE(d0);
    STAGE(d0 + 1);
    LOADW(d0);
    asm volatile("s_waitcnt vmcnt(0)" ::: "memory");

#pragma unroll 1
    for (int i = 0; i < 16; ++i) {
        const int d = d0 + i;

        // [A] drain my stage(d+1); newer ops = 2 stores + 27 wk = 29
        asm volatile("s_waitcnt vmcnt(29)" ::: "memory");
        // [B] all waves' stage(d+1) done; all waves done reading slot (d+2)&3
        asm volatile("s_barrier" ::: "memory");

        // [C] prefetch plane d+2 into slot (d+2)&3 (disjoint from d-1,d,d+1)
        if (i < 15) STAGE(d + 2);

        // [D] compute plane d: one b128 LDS read per (di,hi,cc); halos via DPP
        float acc[2][4];
#pragma unroll
        for (int cc = 0; cc < 2; ++cc)
            acc[cc][0] = acc[cc][1] = acc[cc][2] = acc[cc][3] = 0.f;

#pragma unroll
        for (int di = -1; di <= 1; ++di) {
            const int slot = (d + di) & 3;
#pragma unroll
            for (int hi = -1; hi <= 1; ++hi) {
                const int r  = hl + hi + 1;            // 0..5
                const int kb = (di + 1) * 9 + (hi + 1) * 3;
#pragma unroll
                for (int cc = 0; cc < 2; ++cc) {
                    const float* row = &lds[slot][c0 + cc][r][0];
                    const float4 xv = *(const float4*)(row + w0);
                    const float  xm = dpp_prev(xv.w);   // x[w0-1] (circular)
                    const float  xp = dpp_next(xv.x);   // x[w0+4] (circular)
                    const float4 wa = wk[kb], wm = wk[kb + 1], wc = wk[kb + 2];
                    acc[cc][0] += wa.x * xm;    acc[cc][1] += wa.y * xv.x;
                    acc[cc][2] += wa.z * xv.y;  acc[cc][3] += wa.w * xv.z;
                    acc[cc][0] += wm.x * xv.x;  acc[cc][1] += wm.y * xv.y;
                    acc[cc][2] += wm.z * xv.z;  acc[cc][3] += wm.w * xv.w;
                    acc[cc][0] += wc.x * xv.y;  acc[cc][1] += wc.y * xv.z;
                    acc[cc][2] += wc.z * xv.w;  acc[cc][3] += wc.w * xp;
                }
            }
        }

        // [E] nontemporal stores (out is never re-read) — BEFORE LOADW
#pragma unroll
        for (int cc = 0; cc < 2; ++cc) {
            f32x4 v;
            v.x = acc[cc][0]; v.y = acc[cc][1]; v.z = acc[cc][2]; v.w = acc[cc][3];
            __builtin_nontemporal_store(v,
                (f32x4*)(ob + (size_t)cc * DHW + (size_t)d * HW));
        }

        // [F] wk(d+1) last; fence forbids hoisting the 27-load batch upward
        //     (hoist doubles wk live range -> spill: R6/R7/R10/R11 lesson)
        __builtin_amdgcn_sched_barrier(0);
        if (i < 15) LOADW(d + 1);
    }
}

extern "C" void kernel_launch(void* const* d_in, const int* in_sizes, int n_in,
                              void* d_out, int out_size, void* d_ws, size_t ws_size,
                              hipStream_t stream) {
    const float* x = (const float*)d_in[0];
    const float* w = (const float*)d_in[1];
    float* out = (float*)d_out;
    // grid: b(2) x g(8) x h-tiles(16) x d-chunks(4) = 1024 blocks of 256
    dim3 grid(1024);
    dim3 block(256);
    hipLaunchKernelGGL(ska3d_kernel, grid, block, 0, stream, x, w, out);
}